// Round 1
// baseline (379.537 us; speedup 1.0000x reference)
//
#include <hip/hip_runtime.h>

// DepenL: 3x3 unfold (pad=1, stride=1) of key/query [4,64,128,128] fp32.
// Output reinterpretation: within a (b,c) plane of 9*16384 = 147456 elements,
// flat output index n corresponds to unfold element (p = n>>14, l = n&16383),
// and to logical (i = n/9, j = n%9). Center value C(i) = F[9*i+4].
// out1[n] = F_key[n] * C_qry(n/9);  out2[n] = C_key(n/9) * F_qry[n].

#define LPP   16384     // 128*128 pixels per plane
#define NPP   147456    // 9*LPP output elements per plane per array
#define HW    128

__device__ __forceinline__ int unfold_off(int n, bool& valid) {
    // offset into the 128x128 plane for unfold flat index n; valid=false -> 0
    const int p  = n >> 14;
    const int l  = n & (LPP - 1);
    const int ho = l >> 7;
    const int wo = l & (HW - 1);
    const int ki = p / 3;
    const int kj = p - 3 * ki;
    const int h  = ho + ki - 1;
    const int w  = wo + kj - 1;
    valid = ((unsigned)h < (unsigned)HW) && ((unsigned)w < (unsigned)HW);
    return h * HW + w;
}

extern "C" __global__ __launch_bounds__(256) void depen_kernel(
    const float* __restrict__ key, const float* __restrict__ qry,
    float* __restrict__ out1, float* __restrict__ out2)
{
    const int bc = blockIdx.y;                                   // 0..255 (b*C+c)
    const int n0 = 8 * (blockIdx.x * 256 + threadIdx.x);         // 0..147448, mult of 8

    const float* __restrict__ kp = key + (size_t)bc * LPP;
    const float* __restrict__ qp = qry + (size_t)bc * LPP;

    // ---- main row of 8 unfold values (same p, same input row for all 8) ----
    const int p   = n0 >> 14;            // block-uniform
    const int l0  = n0 & (LPP - 1);
    const int ho  = l0 >> 7;
    const int wo0 = l0 & (HW - 1);       // multiple of 8
    const int ki  = p / 3;
    const int kj  = p - 3 * ki;
    const int h   = ho + ki - 1;

    float kv[8], qv[8];
    if ((unsigned)h < (unsigned)HW) {
        const int boff = h * HW + wo0 + kj - 1;
        #pragma unroll
        for (int e = 1; e < 7; ++e) {    // middle 6 always in-bounds
            kv[e] = kp[boff + e];
            qv[e] = qp[boff + e];
        }
        const bool v0 = (wo0 + kj - 1) >= 0;       // only fails wo0=0,kj=0
        const bool v7 = (wo0 + kj + 6) < HW;       // only fails wo0=120,kj=2
        kv[0] = v0 ? kp[boff]     : 0.0f;
        qv[0] = v0 ? qp[boff]     : 0.0f;
        kv[7] = v7 ? kp[boff + 7] : 0.0f;
        qv[7] = v7 ? qp[boff + 7] : 0.0f;
    } else {
        #pragma unroll
        for (int e = 0; e < 8; ++e) { kv[e] = 0.0f; qv[e] = 0.0f; }
    }

    // ---- center values for the (at most 2) i's this block of 8 spans ----
    const int i0 = n0 / 9;
    const int r  = n0 - 9 * i0;          // 0..8
    const int i1 = (n0 + 7) / 9;         // == i0 or i0+1, always < 16384

    bool va, vb;
    const int offa = unfold_off(9 * i0 + 4, va);
    const int offb = unfold_off(9 * i1 + 4, vb);
    const float ck0 = va ? kp[offa] : 0.0f;
    const float cq0 = va ? qp[offa] : 0.0f;
    const float ck1 = vb ? kp[offb] : 0.0f;
    const float cq1 = vb ? qp[offb] : 0.0f;

    // ---- compute + vectorized store ----
    float o1[8], o2[8];
    #pragma unroll
    for (int e = 0; e < 8; ++e) {
        const bool first = (r + e) < 9;  // element still belongs to i0
        const float cq = first ? cq0 : cq1;
        const float ck = first ? ck0 : ck1;
        o1[e] = kv[e] * cq;
        o2[e] = ck * qv[e];
    }

    float* o1p = out1 + (size_t)bc * NPP + n0;
    float* o2p = out2 + (size_t)bc * NPP + n0;
    reinterpret_cast<float4*>(o1p)[0] = make_float4(o1[0], o1[1], o1[2], o1[3]);
    reinterpret_cast<float4*>(o1p)[1] = make_float4(o1[4], o1[5], o1[6], o1[7]);
    reinterpret_cast<float4*>(o2p)[0] = make_float4(o2[0], o2[1], o2[2], o2[3]);
    reinterpret_cast<float4*>(o2p)[1] = make_float4(o2[4], o2[5], o2[6], o2[7]);
}

extern "C" void kernel_launch(void* const* d_in, const int* in_sizes, int n_in,
                              void* d_out, int out_size, void* d_ws, size_t ws_size,
                              hipStream_t stream) {
    const float* key = (const float*)d_in[0];   // key_map   [4,64,128,128]
    const float* qry = (const float*)d_in[1];   // query_map [4,64,128,128]
    float* out1 = (float*)d_out;                // [4,64,16384,9]
    float* out2 = out1 + (size_t)256 * NPP;     // second tuple element

    // 256 planes (B*C), 147456/8 = 18432 threads/plane = 72 blocks of 256
    dim3 grid(72, 256, 1);
    dim3 block(256, 1, 1);
    depen_kernel<<<grid, block, 0, stream>>>(key, qry, out1, out2);
}

// Round 3
// 375.977 us; speedup vs baseline: 1.0095x; 1.0095x over previous
//
#include <hip/hip_runtime.h>

// DepenL: 3x3 unfold (pad=1, stride=1) of key/query [4,64,128,128] fp32.
// The torch-style .view of [B, C*kk, L] as [B, C, L, kk] is a raw row-major
// reinterpretation: within a (b,c) plane of 9*16384 elements, output flat
// index n corresponds to unfold element (p = n>>14, l = n&16383). The
// "center" slice element (i, j=4) sits at flat index 9*i+4, whose unfold
// coords are p=(9i+4)>>14, l=(9i+4)&16383 — NOT the unfold-center patch.
// (R2 wrongly assumed C(i)=input[i]; R1's gather below is the verified-
// correct form, absmax==0.)
// out1[n] = U_key[n] * C_qry(n/9);  out2[n] = C_key(n/9) * U_qry[n].

#define LPP   16384     // 128*128 pixels per plane
#define NPP   147456    // 9*LPP output elements per plane per array
#define HW    128

__device__ __forceinline__ int unfold_off(int n, bool& valid) {
    // input-plane offset for unfold flat index n; valid=false -> value is 0
    const int p  = n >> 14;
    const int l  = n & (LPP - 1);
    const int ho = l >> 7;
    const int wo = l & (HW - 1);
    const int ki = p / 3;
    const int kj = p - 3 * ki;
    const int h  = ho + ki - 1;
    const int w  = wo + kj - 1;
    valid = ((unsigned)h < (unsigned)HW) && ((unsigned)w < (unsigned)HW);
    return h * HW + w;
}

extern "C" __global__ __launch_bounds__(256) void depen_kernel(
    const float* __restrict__ key, const float* __restrict__ qry,
    float* __restrict__ out1, float* __restrict__ out2)
{
    const int bc = blockIdx.y;                                   // 0..255 (b*C+c)
    const int n0 = 4 * (blockIdx.x * 256 + threadIdx.x);         // mult of 4

    const float* __restrict__ kp = key + (size_t)bc * LPP;
    const float* __restrict__ qp = qry + (size_t)bc * LPP;

    // ---- 4 unfold values (same p, same input row for all 4) ----
    const int p   = n0 >> 14;            // uniform across blockIdx.x groups
    const int l0  = n0 & (LPP - 1);
    const int ho  = l0 >> 7;
    const int wo0 = l0 & (HW - 1);       // multiple of 4
    const int ki  = p / 3;
    const int kj  = p - 3 * ki;
    const int h   = ho + ki - 1;

    float kv[4], qv[4];
    if ((unsigned)h < (unsigned)HW) {
        const int base = h * HW + wo0 + kj - 1;   // w = wo0+kj-1+e
        kv[1] = kp[base + 1];  qv[1] = qp[base + 1];   // always in-bounds
        kv[2] = kp[base + 2];  qv[2] = qp[base + 2];
        const bool v0 = (wo0 + kj) > 0;           // fails only wo0=0,  kj=0
        const bool v3 = (wo0 + kj + 2) < HW;      // fails only wo0=124,kj=2
        kv[0] = v0 ? kp[base]     : 0.0f;
        qv[0] = v0 ? qp[base]     : 0.0f;
        kv[3] = v3 ? kp[base + 3] : 0.0f;
        qv[3] = v3 ? qp[base + 3] : 0.0f;
    } else {
        kv[0]=kv[1]=kv[2]=kv[3]=0.0f;
        qv[0]=qv[1]=qv[2]=qv[3]=0.0f;
    }

    // ---- centers: at most 2 distinct i across 4 consecutive n ----
    const int i0 = n0 / 9;
    const int r  = n0 - 9 * i0;          // 0..8
    const int i1 = (n0 + 3) / 9;         // i0 or i0+1, always < 16384

    bool va, vb;
    const int offa = unfold_off(9 * i0 + 4, va);
    const int offb = unfold_off(9 * i1 + 4, vb);
    const float ck0 = va ? kp[offa] : 0.0f;
    const float cq0 = va ? qp[offa] : 0.0f;
    const float ck1 = vb ? kp[offb] : 0.0f;
    const float cq1 = vb ? qp[offb] : 0.0f;

    // ---- compute + fully-coalesced float4 stores ----
    float o1[4], o2[4];
    #pragma unroll
    for (int e = 0; e < 4; ++e) {
        const bool first = (r + e) < 9;
        const float cq = first ? cq0 : cq1;
        const float ck = first ? ck0 : ck1;
        o1[e] = kv[e] * cq;
        o2[e] = ck * qv[e];
    }

    const size_t ob = (size_t)bc * NPP + n0;
    *reinterpret_cast<float4*>(out1 + ob) = make_float4(o1[0], o1[1], o1[2], o1[3]);
    *reinterpret_cast<float4*>(out2 + ob) = make_float4(o2[0], o2[1], o2[2], o2[3]);
}

extern "C" void kernel_launch(void* const* d_in, const int* in_sizes, int n_in,
                              void* d_out, int out_size, void* d_ws, size_t ws_size,
                              hipStream_t stream) {
    const float* key = (const float*)d_in[0];   // key_map   [4,64,128,128]
    const float* qry = (const float*)d_in[1];   // query_map [4,64,128,128]
    float* out1 = (float*)d_out;                // [4,64,16384,9]
    float* out2 = out1 + (size_t)256 * NPP;     // second tuple element

    // 256 planes (B*C); 147456/4 = 36864 threads/plane = 144 blocks of 256
    dim3 grid(144, 256, 1);
    dim3 block(256, 1, 1);
    depen_kernel<<<grid, block, 0, stream>>>(key, qry, out1, out2);
}